// Round 10
// baseline (336.154 us; speedup 1.0000x reference)
//
#include <hip/hip_runtime.h>
#include <hip/hip_bf16.h>

// ---------------------------------------------------------------------------
// SelfAttention: QKV = X@W ; S = Q K^T / sqrt(512) ; P = softmax(S, axis=q) ;
// out = P @ V.   B=4, S=4096, D_IN=1024, A=512, O=1024.
// Softmax over the *q* axis (per key column).  Materialize P = exp(S)
// (unnormalized bf16, TILED layout [bl][ki][q][256]); fold 1/l into Vt;
// out = P @ Vt'.  All GEMMs: 256x256 tile, BK=64, 32x32x16 MFMA, 8-phase
// schedule with SINGLE barrier/phase and post-barrier ds_read-ahead:
// phase = { reads for phase i+1 | stages | lgkmcnt(R) | 8 MFMA on phase-i
// frags | [vmcnt ckpt] | barrier }.  LDS drain overlaps the MFMA cluster.
// ---------------------------------------------------------------------------

typedef unsigned int u32;
typedef unsigned short u16;
typedef __bf16 bf16x8 __attribute__((ext_vector_type(8)));
typedef float f32x16 __attribute__((ext_vector_type(16)));
typedef u16 ushort8_t __attribute__((ext_vector_type(8)));

#define SCL 0.04419417382415922f   // 1/sqrt(512)

#define GLOAD16(gp, lp)                                                        \
  __builtin_amdgcn_global_load_lds(                                            \
      (const __attribute__((address_space(1))) u32*)(gp),                      \
      (__attribute__((address_space(3))) u32*)(lp), 16, 0, 0)

#define VMW(N) asm volatile("s_waitcnt vmcnt(" #N ")" ::: "memory")
#define LGW(N)                                                                 \
  do {                                                                         \
    asm volatile("s_waitcnt lgkmcnt(" #N ")" ::: "memory");                    \
    __builtin_amdgcn_sched_barrier(0);                                         \
  } while (0)
#define BARX                                                                   \
  do {                                                                         \
    __builtin_amdgcn_s_barrier();                                              \
    __builtin_amdgcn_sched_barrier(0);                                         \
  } while (0)

__device__ __forceinline__ u16 f2bf(float f) {
  union { float f; u32 u; } v; v.f = f;
  u32 r = (v.u + 0x7fffu + ((v.u >> 16) & 1u)) >> 16;   // RNE
  return (u16)r;
}
__device__ __forceinline__ float bf2f(u16 h) {
  union { u32 u; float f; } v; v.u = ((u32)h) << 16;
  return v.f;
}

// ---------------- K1: X fp32 -> bf16  AND  W -> Wbt (transposed) -----------
__global__ __launch_bounds__(256) void k_cvt(const float* __restrict__ X,
                                             const float* __restrict__ W,
                                             u16* __restrict__ Xb,
                                             u16* __restrict__ Wbt) {
  __shared__ float t[64][65];
  const int bid = blockIdx.x;
  if (bid < 8192) {
    size_t i = ((size_t)bid * 256 + threadIdx.x) * 8;
    const float4* p = (const float4*)(X + i);
    float4 a = p[0], b = p[1];
    ushort8_t o;
    o[0] = f2bf(a.x); o[1] = f2bf(a.y); o[2] = f2bf(a.z); o[3] = f2bf(a.w);
    o[4] = f2bf(b.x); o[5] = f2bf(b.y); o[6] = f2bf(b.z); o[7] = f2bf(b.w);
    *(ushort8_t*)(Xb + i) = o;
  } else {
    const int b2 = bid - 8192;
    const int e0 = (b2 & 31) * 64, d0 = (b2 >> 5) * 64;
    const int c = threadIdx.x & 63, r4 = threadIdx.x >> 6;
#pragma unroll
    for (int i = 0; i < 16; i++) {
      int d = r4 + i * 4;
      t[d][c] = W[(size_t)(d0 + d) * 2048 + e0 + c];
    }
    __syncthreads();
#pragma unroll
    for (int i = 0; i < 16; i++) {
      int e = r4 + i * 4;
      Wbt[(size_t)(e0 + e) * 1024 + d0 + c] = f2bf(t[c][e]);
    }
  }
}

// ---------------------------------------------------------------------------
// 8-phase GEMM, 32x32x16 MFMA, read-ahead one phase, 1 barrier/phase.
// C(256x256) = A(256xK) * B(256xK)^T, BK=64, NT K-tiles (even, >=4).
// AM=0: A rows linear stride lda.  AM=1: A = tiled-P [ki][4096][256]
// (row stride 256, kt offset = (kt>>2)<<20 | (kt&3)<<6).
// LDS 128KB: A slots @0/32KB (kt parity), B slots @64/96KB; 16B chunk c of
// row r holds global chunk c^(r&7) (measured conflict-free).
// Waves 2(wr) x 4(wc); per-wave C = 128x64 = acc[4 mf][2 nf] f32x16.
// A frag (mf,kk): row wr*128+mf*32+(l&31), chunk kk*2+(l>>5).
// Staging per iter (kt even): p1:A(kt+1)L p2:B(kt+2)h0 p3:B(kt+2)h1
// p4:A(kt+2)E p5:A(kt+2)L p6:B(kt+3)h0 p7:B(kt+3)h1 p8:A(kt+3)E
// (E = rows {0-63,128-191}, L = {64-127,192-255}).
// Checkpoints: VMW(4)@p3 (slot1=kt+1 fully landed, read from p4),
// VMW(4)@p7 (slot0=kt+2 landed, read from p8).  Steady-state 6 in flight.
// ---------------------------------------------------------------------------
template <int AM>
__device__ __forceinline__ void gemm8(const u16* __restrict__ Ab,
                                      const u16* __restrict__ Bb,
                                      int lda, int ldb, int NT,
                                      u16* lds, f32x16 (&acc)[4][2]) {
  const int tid = threadIdx.x;
  const int w = tid >> 6, l = tid & 63;
  const int l31 = l & 31, hi = l >> 5;
  const int wr = w >> 2, wc = w & 3;

  const int gcs = (tid & 7) ^ ((tid >> 3) & 7);
  const u16* pA = Ab + (size_t)(tid >> 3) * lda + gcs * 8;
  const u16* pB = Bb + (size_t)(tid >> 3) * ldb + gcs * 8;

  bf16x8 aX[4], aY[4];        // A frag sets (ping-pong per phase)
  bf16x8 bX[2][4], bY[2][4];  // B frag sets (per K-tile parity)

  auto stA = [&](int kt, int R) {
    size_t ko = (AM == 1) ? (size_t)(((kt >> 2) << 20) | ((kt & 3) << 6))
                          : (size_t)kt * 64;
    GLOAD16(pA + (size_t)R * lda + ko,
            lds + ((kt & 1) << 14) + R * 64 + (w << 9));
  };
  auto stB = [&](int kt, int R) {
    GLOAD16(pB + (size_t)R * ldb + (size_t)kt * 64,
            lds + 32768 + ((kt & 1) << 14) + R * 64 + (w << 9));
  };
  auto rdA = [&](bf16x8 (&a)[4], int asl, int mf) {
    int r = wr * 128 + mf * 32 + l31;
    const u16* base = lds + (asl << 14) + r * 64;
#pragma unroll
    for (int kk = 0; kk < 4; kk++) {
      int c = (kk * 2 + hi) ^ (r & 7);
      a[kk] = *(const bf16x8*)(base + c * 8);
    }
  };
  auto rdB = [&](bf16x8 (&b)[2][4], int bsl) {
#pragma unroll
    for (int nf = 0; nf < 2; nf++) {
      int r = wc * 64 + nf * 32 + l31;
      const u16* base = lds + 32768 + (bsl << 14) + r * 64;
#pragma unroll
      for (int kk = 0; kk < 4; kk++) {
        int c = (kk * 2 + hi) ^ (r & 7);
        b[nf][kk] = *(const bf16x8*)(base + c * 8);
      }
    }
  };
  auto mf8 = [&](int mf, bf16x8 (&a)[4], bf16x8 (&b)[2][4]) {
    __builtin_amdgcn_s_setprio(1);
#pragma unroll
    for (int kk = 0; kk < 4; kk++)
#pragma unroll
      for (int nf = 0; nf < 2; nf++)
        acc[mf][nf] = __builtin_amdgcn_mfma_f32_32x32x16_bf16(
            a[kk], b[nf][kk], acc[mf][nf], 0, 0, 0);
    __builtin_amdgcn_s_setprio(0);
  };

  // prologue: B(0)x4, A(0)x4, B(1)x4, A(1)E (14 loads); VMW(6) -> slot0
  // landed, {B(1),A(1)E}=6 outstanding = steady-state entry.  Seed frags.
  stB(0, 0); stB(0, 64); stB(0, 128); stB(0, 192);
  stA(0, 0); stA(0, 128); stA(0, 64); stA(0, 192);
  stB(1, 0); stB(1, 64); stB(1, 128); stB(1, 192);
  stA(1, 0); stA(1, 128);
  VMW(6);
  BARX;
  rdB(bX, 0); rdA(aX, 0, 0);

  const int NI = NT >> 1;
  for (int i = 0; i < NI - 1; i++) {
    const int kt = 2 * i;
    // p1: consume (slot0, mf0); read mf1
    rdA(aY, 0, 1); stA(kt + 1, 64); stA(kt + 1, 192);
    LGW(4); mf8(0, aX, bX); BARX;
    // p2
    rdA(aX, 0, 2); stB(kt + 2, 0); stB(kt + 2, 64);
    LGW(4); mf8(1, aY, bX); BARX;
    // p3   [VMW(4): slot1 (kt+1) fully landed for p4..p8 reads]
    rdA(aY, 0, 3); stB(kt + 2, 128); stB(kt + 2, 192);
    LGW(4); mf8(2, aX, bX); VMW(4); BARX;
    // p4: read slot1 B + mf0
    rdB(bY, 1); rdA(aX, 1, 0); stA(kt + 2, 0); stA(kt + 2, 128);
    LGW(12); mf8(3, aY, bX); BARX;
    // p5
    rdA(aY, 1, 1); stA(kt + 2, 64); stA(kt + 2, 192);
    LGW(4); mf8(0, aX, bY); BARX;
    // p6
    rdA(aX, 1, 2); stB(kt + 3, 0); stB(kt + 3, 64);
    LGW(4); mf8(1, aY, bY); BARX;
    // p7   [VMW(4): slot0 (kt+2) fully landed for p8+ reads]
    rdA(aY, 1, 3); stB(kt + 3, 128); stB(kt + 3, 192);
    LGW(4); mf8(2, aX, bY); VMW(4); BARX;
    // p8: read slot0 B(kt+2) + mf0
    rdB(bX, 0); rdA(aX, 0, 0); stA(kt + 3, 0); stA(kt + 3, 128);
    LGW(12); mf8(3, aY, bY); BARX;
  }
  // tail iter (kt = NT-2): p1 stages A(NT-1)L; VMW(0)@p3; no further stages.
  {
    rdA(aY, 0, 1); stA(NT - 1, 64); stA(NT - 1, 192);
    LGW(4); mf8(0, aX, bX); BARX;
    rdA(aX, 0, 2);
    LGW(4); mf8(1, aY, bX); BARX;
    rdA(aY, 0, 3);
    LGW(4); mf8(2, aX, bX); VMW(0); BARX;
    rdB(bY, 1); rdA(aX, 1, 0);
    LGW(12); mf8(3, aY, bX); BARX;
    rdA(aY, 1, 1);
    LGW(4); mf8(0, aX, bY); BARX;
    rdA(aX, 1, 2);
    LGW(4); mf8(1, aY, bY); BARX;
    rdA(aY, 1, 3);
    LGW(4); mf8(2, aX, bY); BARX;
    LGW(0); mf8(3, aY, bY);
  }
}

// C/D row map for 32x32: row = (j&3) + 8*(j>>2) + 4*hi  (j = reg 0..15)
#define QR(j, hi) (((j) & 3) + 8 * ((j) >> 2) + 4 * (hi))

// ---------------- K3: QKV GEMM (8-phase, 256x256, region-split) ------------
// h=0 (e<1024): A=X, B=W  -> acc rows=s(reg), cols=e(lane) -> QK[s][e],
//   32-lane-contiguous ushort stores, no Q/K branch (merged buffer).
// h=1 (V): A=W(Vcols), B=X -> acc rows=o, cols=s -> Vt[o][s].
__global__ __launch_bounds__(512, 2) void k_qkv(const u16* __restrict__ Xb,
                                                const u16* __restrict__ Wbt,
                                                u16* __restrict__ QK,
                                                u16* __restrict__ Vt) {
  __shared__ u16 lds[65536];
  const int cpx = 64;                    // nwg = 512
  const int swz = ((int)blockIdx.x & 7) * cpx + ((int)blockIdx.x >> 3);
  const int c8 = swz & 7, ri = swz >> 3;
  const int ci4 = c8 & 3, h = c8 >> 2;
  const int tid = threadIdx.x;
  const int w = tid >> 6, l = tid & 63;
  const int l31 = l & 31, hi = l >> 5;
  const int wr = w >> 2, wc = w & 3;
  f32x16 acc[4][2] = {};
  const int bb = ri >> 4;
  const int sbase = (ri * 256) & 4095;
  if (h == 0) {
    gemm8<0>(Xb + (size_t)(ri * 256) * 1024, Wbt + (size_t)(ci4 * 256) * 1024,
             1024, 1024, 16, lds, acc);
#pragma unroll
    for (int mf = 0; mf < 4; mf++)
#pragma unroll
      for (int nf = 0; nf < 2; nf++) {
        int e = ci4 * 256 + wc * 64 + nf * 32 + l31;
#pragma unroll
        for (int j = 0; j < 16; j++) {
          int s = sbase + wr * 128 + mf * 32 + QR(j, hi);
          QK[((size_t)bb * 4096 + s) * 1024 + e] = f2bf(acc[mf][nf][j]);
        }
      }
  } else {
    gemm8<0>(Wbt + (size_t)(1024 + ci4 * 256) * 1024,
             Xb + (size_t)(ri * 256) * 1024, 1024, 1024, 16, lds, acc);
#pragma unroll
    for (int mf = 0; mf < 4; mf++)
#pragma unroll
      for (int nf = 0; nf < 2; nf++) {
        int s = sbase + wc * 64 + nf * 32 + l31;
#pragma unroll
        for (int j = 0; j < 16; j++) {
          int o = ci4 * 256 + wr * 128 + mf * 32 + QR(j, hi);
          Vt[((size_t)bb * 1024 + o) * 4096 + s] = f2bf(acc[mf][nf][j]);
        }
      }
  }
}

// ---------------- K4: S-GEMM + exp -> tiled P, column sums ------------------
// A = Q rows (m-dir = q), B = K rows (n-dir = k, 32-lane contiguous).
// P[q][k] stores are lane-contiguous ushorts; column sums (over q) are
// per-lane partials + shfl_xor(32) + tiny LDS cross-wave pass.
__global__ __launch_bounds__(512, 2) void k_sp(const u16* __restrict__ QK,
                                               u16* __restrict__ P,
                                               float* __restrict__ part,
                                               int b0, int nwg) {
  __shared__ u16 lds[65536];
  const int cpx = nwg >> 3;
  const int swz = ((int)blockIdx.x & 7) * cpx + ((int)blockIdx.x >> 3);
  const int ki = swz & 15, qi = (swz >> 4) & 15, bl = swz >> 8;
  const int b = b0 + bl;
  const int q0 = qi * 256;

  f32x16 acc[4][2] = {};
  gemm8<0>(QK + ((size_t)b * 4096 + q0) * 1024,              // A = Q rows
           QK + ((size_t)b * 4096 + ki * 256) * 1024 + 512,  // B = K rows
           1024, 1024, 8, lds, acc);

  const int tid = threadIdx.x;
  const int w = tid >> 6, l = tid & 63;
  const int l31 = l & 31, hi = l >> 5;
  const int wr = w >> 2, wc = w & 3;

  u16* Pb = P + (size_t)bl * 16777216 + (size_t)ki * 1048576;
  float ps[2] = {0.f, 0.f};
#pragma unroll
  for (int mf = 0; mf < 4; mf++)
#pragma unroll
    for (int nf = 0; nf < 2; nf++) {
      int kc = wc * 64 + nf * 32 + l31;
#pragma unroll
      for (int j = 0; j < 16; j++) {
        int q = q0 + wr * 128 + mf * 32 + QR(j, hi);
        float p = __expf(acc[mf][nf][j] * SCL);
        Pb[(size_t)q * 256 + kc] = f2bf(p);
        ps[nf] += p;
      }
    }
  // sum over this wave's 128 q rows: hi/lo halves hold disjoint q, same k
  ps[0] += __shfl_xor(ps[0], 32);
  ps[1] += __shfl_xor(ps[1], 32);
  __syncthreads();                       // gemm8 done; reuse lds as red[]
  float* red = (float*)lds;              // [2][256]
  if (l < 32) {
    red[wr * 256 + wc * 64 + l31] = ps[0];
    red[wr * 256 + wc * 64 + 32 + l31] = ps[1];
  }
  __syncthreads();
  if (tid < 256)
    part[((size_t)(bl * 16 + qi)) * 4096 + ki * 256 + tid] =
        red[tid] + red[256 + tid];
}

// ---------------- K5: linv + Vt scale (fused) ------------------------------
__global__ __launch_bounds__(256) void k_scale(u16* __restrict__ Vtg,
                                               const float* __restrict__ part) {
  __shared__ float linv[256];
  const int bl = blockIdx.x >> 4, kb = blockIdx.x & 15, ob = blockIdx.y;
  const int t = threadIdx.x;
  float s = 0.f;
#pragma unroll
  for (int qb = 0; qb < 16; qb++)
    s += part[((size_t)(bl * 16 + qb)) * 4096 + kb * 256 + t];
  linv[t] = 1.0f / s;
  __syncthreads();
  u16* base = Vtg + ((size_t)bl * 1024 + ob * 256) * 4096 + kb * 256;
#pragma unroll 4
  for (int i = 0; i < 32; i++) {
    int idx = i * 256 + t;
    int r = idx >> 5, kk = (idx & 31) * 8;
    ushort8_t v = *(ushort8_t*)&base[(size_t)r * 4096 + kk];
#pragma unroll
    for (int j = 0; j < 8; j++) v[j] = f2bf(bf2f(v[j]) * linv[kk + j]);
    *(ushort8_t*)&base[(size_t)r * 4096 + kk] = v;
  }
}

// ---------------- K6: out = P(tiled) @ Vt'  (8-phase, 256x256) -------------
__global__ __launch_bounds__(512, 2) void k_pv(const u16* __restrict__ P,
                                               const u16* __restrict__ Vtg,
                                               float* __restrict__ outg,
                                               int nwg) {
  __shared__ u16 lds[65536];
  const int cpx = nwg >> 3;
  const int swz = ((int)blockIdx.x & 7) * cpx + ((int)blockIdx.x >> 3);
  const int oi = swz & 3, qi = (swz >> 2) & 15, bl = swz >> 6;
  const int q0 = qi * 256, o0 = oi * 256;

  f32x16 acc[4][2] = {};
  gemm8<1>(P + (size_t)bl * 16777216 + (size_t)q0 * 256,
           Vtg + ((size_t)bl * 1024 + o0) * 4096, 256, 4096, 64, lds, acc);

  const int tid = threadIdx.x;
  const int w = tid >> 6, l = tid & 63;
  const int l31 = l & 31, hi = l >> 5;
  const int wr = w >> 2, wc = w & 3;
#pragma unroll
  for (int mf = 0; mf < 4; mf++)
#pragma unroll
    for (int nf = 0; nf < 2; nf++) {
      int o = o0 + wc * 64 + nf * 32 + l31;
#pragma unroll
      for (int j = 0; j < 16; j++) {
        int q = q0 + wr * 128 + mf * 32 + QR(j, hi);
        outg[((size_t)bl * 4096 + q) * 1024 + o] = acc[mf][nf][j];
      }
    }
}

// ---------------------------------------------------------------------------
extern "C" void kernel_launch(void* const* d_in, const int* in_sizes, int n_in,
                              void* d_out, int out_size, void* d_ws, size_t ws_size,
                              hipStream_t stream) {
  const float* X = (const float*)d_in[0];   // 4*4096*1024
  const float* W = (const float*)d_in[1];   // 1024*2048
  float* out = (float*)d_out;               // 4*4096*1024 fp32
  char* ws = (char*)d_ws;

  int G;
  if (ws_size >= 203489280ull)      G = 4;
  else if (ws_size >= 135299072ull) G = 2;
  else if (ws_size >= 104857600ull) G = 1;
  else return;
  const size_t PB = (size_t)G * 33554432ull;

  // layout (bytes):
  //   QK @ 0          (32MB)   bf16 [4][4096][1024]  (cols 0-511 Q, 512-1023 K)
  //   Vt @ 32MB       (32MB)   bf16 [4][1024][4096]
  //   P  @ 64MB       (PB)     bf16 TILED [G][16 ki][4096 q][256 k]
  //   Xb @ 64MB       (32MB)   aliases P (dead after k_qkv)
  //   Wbt@ 96MB       (4MB)    aliases P (dead after k_qkv)
  //   part @ 64MB+PB  (G*256KB) f32 [G][16][4096]
  u16* QK  = (u16*)(ws);
  u16* Vt  = (u16*)(ws + 33554432);
  u16* P   = (u16*)(ws + 67108864);
  u16* Xb  = (u16*)(ws + 67108864);
  u16* Wbt = (u16*)(ws + 100663296);
  float* part = (float*)(ws + 67108864 + PB);

  k_cvt<<<dim3(8704), dim3(256), 0, stream>>>(X, W, Xb, Wbt);
  k_qkv<<<dim3(512), dim3(512), 0, stream>>>(Xb, Wbt, QK, Vt);
  for (int b0 = 0; b0 < 4; b0 += G) {
    int nwg_sp = 256 * G;
    k_sp<<<dim3(nwg_sp), dim3(512), 0, stream>>>(QK, P, part, b0, nwg_sp);
    k_scale<<<dim3(G * 16, 4), dim3(256), 0, stream>>>(Vt + (size_t)b0 * 4194304, part);
    int nwg = 64 * G;
    k_pv<<<dim3(nwg), dim3(512), 0, stream>>>(P, Vt + (size_t)b0 * 4194304,
                                              out + (size_t)b0 * 4194304, nwg);
  }
}